// Round 3
// baseline (577.155 us; speedup 1.0000x reference)
//
#include <hip/hip_runtime.h>
#include <hip/hip_bf16.h>
#include <math.h>

#define GN 8192
#define GD 128
#define GH 2
#define GK 3
#define NEG_SLOPE 0.2f
#define LN_EPS 1e-5f

__device__ __forceinline__ float wred(float v) {
    #pragma unroll
    for (int o = 32; o > 0; o >>= 1) v += __shfl_xor(v, o, 64);
    return v;
}

__global__ void k_zero(int* p, int n) {
    int t = blockIdx.x * 256 + threadIdx.x;
    if (t < n) p[t] = 0;
}

// per-row squared norm. One wave per row.
__global__ void k_prep(const float* __restrict__ x, float* __restrict__ sq) {
    int row = blockIdx.x * 4 + (threadIdx.x >> 6);
    int lane = threadIdx.x & 63;
    const float* xr = x + (size_t)row * GD;
    float a = xr[lane], b = xr[lane + 64];
    float s = wred(a * a + b * b);
    if (lane == 0) sq[row] = s;
}

// fused xp = x@W and attention dots a_s,a_d; 16 nodes per block, col t per thread.
__global__ void k_attn(const float* __restrict__ x,
                       const float* __restrict__ W,
                       const float* __restrict__ att_src,
                       const float* __restrict__ att_dst,
                       float* __restrict__ a_s, float* __restrict__ a_d) {
    __shared__ float xs[16][GD];       // 8 KB
    __shared__ float xpls[16][256];    // 16 KB
    int t = threadIdx.x;
    int i0 = blockIdx.x * 16;
    #pragma unroll
    for (int s = 0; s < 2; s++) {      // 16*128 floats = 512 float4
        int f = t + 256 * s;
        int r = f >> 5, c4 = (f & 31) << 2;
        *(float4*)&xs[r][c4] = *(const float4*)(x + (size_t)(i0 + r) * GD + c4);
    }
    __syncthreads();
    float acc[16];
    #pragma unroll
    for (int r = 0; r < 16; r++) acc[r] = 0.f;
    for (int d = 0; d < GD; d++) {
        float wv = W[d * 256 + t];
        #pragma unroll
        for (int r = 0; r < 16; r++) acc[r] += xs[r][d] * wv;
    }
    #pragma unroll
    for (int r = 0; r < 16; r++) xpls[r][t] = acc[r];
    __syncthreads();
    // 32 jobs (r,h); 4 waves x 8 jobs
    int wid = t >> 6, lane = t & 63;
    for (int jj = 0; jj < 8; jj++) {
        int job = wid * 8 + jj;
        int r = job >> 1, h = job & 1;
        float v0 = xpls[r][h * 128 + lane];
        float v1 = xpls[r][h * 128 + 64 + lane];
        float s = v0 * att_src[h * GD + lane] + v1 * att_src[h * GD + lane + 64];
        float d = v0 * att_dst[h * GD + lane] + v1 * att_dst[h * GD + lane + 64];
        s = wred(s); d = wred(d);
        if (lane == 0) { a_s[(i0 + r) * 2 + h] = s; a_d[(i0 + r) * 2 + h] = d; }
    }
}

// Fused distance + per-row top-3. Block: 32 rows x one j-half (4096).
// Thread: 2 rows x 4 j per 64-wide j-tile.
__launch_bounds__(256, 2)
__global__ void k_knn(const float* __restrict__ x, const float* __restrict__ sq,
                      float* __restrict__ pv, int* __restrict__ pi) {
    __shared__ float xi[32][132];
    __shared__ float xj[64][132];
    __shared__ float sqj[64];
    int t = threadIdx.x;
    int half = blockIdx.x & 1;
    int ib = (blockIdx.x >> 1) * 32;
    int jbase = half * 4096;
    int rg = t >> 4;          // 0..15
    int jl = t & 15;          // 0..15
    int r0 = rg * 2, r1 = r0 + 1;

    #pragma unroll
    for (int s = 0; s < 4; s++) {       // 32*128 floats = 1024 float4
        int f = t + 256 * s;
        int r = f >> 5, c4 = (f & 31) << 2;
        *(float4*)&xi[r][c4] = *(const float4*)(x + (size_t)(ib + r) * GD + c4);
    }
    float si0 = sq[ib + r0], si1 = sq[ib + r1];

    float b0[2] = {1e30f, 1e30f}, b1[2] = {1e30f, 1e30f}, b2[2] = {1e30f, 1e30f};
    int   q0[2] = {0x7fffffff, 0x7fffffff}, q1[2] = {0x7fffffff, 0x7fffffff},
          q2[2] = {0x7fffffff, 0x7fffffff};

    for (int jt = 0; jt < 4096; jt += 64) {
        __syncthreads();
        #pragma unroll
        for (int s = 0; s < 8; s++) {   // 64*128 floats = 2048 float4
            int f = t + 256 * s;
            int r = f >> 5, c4 = (f & 31) << 2;
            *(float4*)&xj[r][c4] = *(const float4*)(x + (size_t)(jbase + jt + r) * GD + c4);
        }
        if (t < 64) sqj[t] = sq[jbase + jt + t];
        __syncthreads();

        float acc[2][4];
        #pragma unroll
        for (int a = 0; a < 2; a++)
            #pragma unroll
            for (int m = 0; m < 4; m++) acc[a][m] = 0.f;

        for (int d4 = 0; d4 < 32; d4++) {
            float4 a0 = *(float4*)&xi[r0][d4 * 4];
            float4 a1 = *(float4*)&xi[r1][d4 * 4];
            #pragma unroll
            for (int m = 0; m < 4; m++) {
                float4 bv = *(float4*)&xj[jl + 16 * m][d4 * 4];
                acc[0][m] += a0.x * bv.x + a0.y * bv.y + a0.z * bv.z + a0.w * bv.w;
                acc[1][m] += a1.x * bv.x + a1.y * bv.y + a1.z * bv.z + a1.w * bv.w;
            }
        }

        #pragma unroll
        for (int rr = 0; rr < 2; rr++) {
            float siv = rr ? si1 : si0;
            #pragma unroll
            for (int m = 0; m < 4; m++) {
                int j = jbase + jt + jl + 16 * m;   // strictly ascending per thread
                float v = (siv + sqj[jl + 16 * m]) - 2.f * acc[rr][m];
                if (v < b2[rr]) {
                    if (v < b1[rr]) {
                        b2[rr] = b1[rr]; q2[rr] = q1[rr];
                        if (v < b0[rr]) { b1[rr] = b0[rr]; q1[rr] = q0[rr]; b0[rr] = v; q0[rr] = j; }
                        else            { b1[rr] = v; q1[rr] = j; }
                    } else { b2[rr] = v; q2[rr] = j; }
                }
            }
        }
    }

    __syncthreads();
    // merge 16 per-row lists of 3 via LDS (reuse xj space)
    float* mv = (float*)&xj[0][0];      // floats 0..1535
    int*   mi = (int*)&xj[16][0];       // floats 2112.., no overlap
    #pragma unroll
    for (int rr = 0; rr < 2; rr++) {
        int row = r0 + rr;
        mv[row * 48 + jl * 3 + 0] = b0[rr]; mi[row * 48 + jl * 3 + 0] = q0[rr];
        mv[row * 48 + jl * 3 + 1] = b1[rr]; mi[row * 48 + jl * 3 + 1] = q1[rr];
        mv[row * 48 + jl * 3 + 2] = b2[rr]; mi[row * 48 + jl * 3 + 2] = q2[rr];
    }
    __syncthreads();
    if (t < 32) {
        int row = t;
        float v0 = 1e30f, v1 = 1e30f, v2 = 1e30f;
        int   i0 = 0x7fffffff, i1 = 0x7fffffff, i2 = 0x7fffffff;
        for (int c = 0; c < 48; c++) {
            float v = mv[row * 48 + c]; int id = mi[row * 48 + c];
            if (v < v2 || (v == v2 && id < i2)) {
                if (v < v1 || (v == v1 && id < i1)) {
                    v2 = v1; i2 = i1;
                    if (v < v0 || (v == v0 && id < i0)) { v1 = v0; i1 = i0; v0 = v; i0 = id; }
                    else                                 { v1 = v; i1 = id; }
                } else { v2 = v; i2 = id; }
            }
        }
        int g = ib + row;
        int base = (g * 2 + half) * 3;
        pv[base] = v0; pv[base + 1] = v1; pv[base + 2] = v2;
        pi[base] = i0; pi[base + 1] = i1; pi[base + 2] = i2;
    }
}

__global__ void k_knn_merge(const float* __restrict__ pv, const int* __restrict__ pi,
                            int* __restrict__ fidx) {
    int row = blockIdx.x * 256 + threadIdx.x;
    float v0 = 1e30f, v1 = 1e30f, v2 = 1e30f;
    int   i0 = 0x7fffffff, i1 = 0x7fffffff, i2 = 0x7fffffff;
    #pragma unroll
    for (int c = 0; c < 6; c++) {
        float v = pv[row * 6 + c]; int id = pi[row * 6 + c];
        if (v < v2 || (v == v2 && id < i2)) {
            if (v < v1 || (v == v1 && id < i1)) {
                v2 = v1; i2 = i1;
                if (v < v0 || (v == v0 && id < i0)) { v1 = v0; i1 = i0; v0 = v; i0 = id; }
                else                                 { v1 = v; i1 = id; }
            } else { v2 = v; i2 = id; }
        }
    }
    fidx[row * 3 + 0] = i0; fidx[row * 3 + 1] = i1; fidx[row * 3 + 2] = i2;
}

__device__ __forceinline__ int clampN(int v) {
    return v < 0 ? 0 : (v >= GN ? GN - 1 : v);   // defensive: garbage -> wrong answer, not fault
}

__global__ void k_count(const int* __restrict__ fidx, int* __restrict__ cnt) {
    int eid = blockIdx.x * 256 + threadIdx.x;   // < 24576
    atomicAdd(&cnt[clampN(fidx[eid])], 1);
}

// single-block exclusive scan of cnt[8192] -> offs[0..8192]
__global__ void k_scan(const int* __restrict__ cnt, int* __restrict__ offs) {
    __shared__ int part[256];
    int t = threadIdx.x;
    int base = t * 32;
    int loc[32];
    int s = 0;
    #pragma unroll
    for (int k = 0; k < 32; k++) { loc[k] = s; s += cnt[base + k]; }
    part[t] = s;
    __syncthreads();
    if (t == 0) {
        int run = 0;
        for (int k = 0; k < 256; k++) { int v = part[k]; part[k] = run; run += v; }
        offs[GN] = run;
    }
    __syncthreads();
    int b = part[t];
    #pragma unroll
    for (int k = 0; k < 32; k++) offs[base + k] = b + loc[k];
}

__global__ void k_fill(const int* __restrict__ fidx, const int* __restrict__ offs,
                       int* __restrict__ cursor, int* __restrict__ elist) {
    int eid = blockIdx.x * 256 + threadIdx.x;   // < 24576
    int i = clampN(fidx[eid]);
    int pos = atomicAdd(&cursor[i], 1);
    int slot = offs[i] + pos;
    if (slot < GN * GK) elist[slot] = eid / 3;  // src node
}

// per-dst gather: softmax over incoming edges, z_h = sum(w*x[src]),
// out = x + relu(LN(mean_h((z_h@W_h)/den_h) + bias))
__global__ void k_gather(const int* __restrict__ offs, const int* __restrict__ elist,
                         const float* __restrict__ a_s, const float* __restrict__ a_d,
                         const float* __restrict__ x,
                         const float* __restrict__ W,
                         const float* __restrict__ bias,
                         const float* __restrict__ gamma,
                         const float* __restrict__ beta,
                         float* __restrict__ out) {
    __shared__ float red[256];
    __shared__ float zs[2][GD];
    __shared__ float os[256];
    int i = blockIdx.x, t = threadIdx.x;
    int h = t >> 7, c = t & 127;
    int start = offs[i];
    int deg = offs[i + 1] - start;
    float adh = a_d[i * 2 + h];

    // pass 1: per-head max
    float mx = -1e30f;
    for (int k = c; k < deg; k += 128) {
        int j = elist[start + k];
        float e = a_s[j * 2 + h] + adh;
        e = e >= 0.f ? e : NEG_SLOPE * e;
        mx = fmaxf(mx, e);
    }
    red[t] = mx;
    __syncthreads();
    #pragma unroll
    for (int s2 = 64; s2 > 0; s2 >>= 1) {
        if (c < s2) red[t] = fmaxf(red[t], red[t + s2]);
        __syncthreads();
    }
    float mh = red[h * 128];
    __syncthreads();

    // pass 2: per-head denom
    float sm = 0.f;
    for (int k = c; k < deg; k += 128) {
        int j = elist[start + k];
        float e = a_s[j * 2 + h] + adh;
        e = e >= 0.f ? e : NEG_SLOPE * e;
        sm += expf(e - mh);
    }
    red[t] = sm;
    __syncthreads();
    #pragma unroll
    for (int s2 = 64; s2 > 0; s2 >>= 1) {
        if (c < s2) red[t] += red[t + s2];
        __syncthreads();
    }
    float dh = red[h * 128];
    __syncthreads();

    // pass 3: z_h[c] = sum_j w_jh * x[j][c]
    float z = 0.f;
    for (int k = 0; k < deg; k++) {
        int j = elist[start + k];
        float e = a_s[j * 2 + h] + adh;
        e = e >= 0.f ? e : NEG_SLOPE * e;
        float w = expf(e - mh);
        z += w * x[(size_t)j * GD + c];
    }
    zs[h][c] = z;
    __syncthreads();

    // matvec: o[t] = (z_h . W[:, t]) / dh   (head h = t>>7 owns cols t)
    float o = 0.f;
    for (int d = 0; d < GD; d++) o += zs[h][d] * W[d * 256 + t];
    o /= dh;
    os[t] = o;
    __syncthreads();

    // head mean + bias, then LN + ReLU + residual (threads t<128 own dim c)
    float y = 0.f;
    if (t < 128) y = 0.5f * (os[c] + os[c + 128]) + bias[c];
    float ps = (t < 128) ? y : 0.f;
    ps = wred(ps);
    if ((t & 63) == 0) red[t >> 6] = ps;
    __syncthreads();
    float mu = (red[0] + red[1] + red[2] + red[3]) * (1.f / 128.f);
    float cg = (t < 128) ? (y - mu) : 0.f;
    float pv2 = wred(cg * cg);
    if ((t & 63) == 0) red[8 + (t >> 6)] = pv2;
    __syncthreads();
    float var = (red[8] + red[9] + red[10] + red[11]) * (1.f / 128.f);
    if (t < 128) {
        float rs = 1.f / sqrtf(var + LN_EPS);
        float nv = cg * rs * gamma[c] + beta[c];
        nv = nv > 0.f ? nv : 0.f;
        out[(size_t)i * GD + c] = x[(size_t)i * GD + c] + nv;
    }
}

extern "C" void kernel_launch(void* const* d_in, const int* in_sizes, int n_in,
                              void* d_out, int out_size, void* d_ws, size_t ws_size,
                              hipStream_t stream) {
    const float* x       = (const float*)d_in[0];
    // d_in[1] = labels (unused)
    const float* W       = (const float*)d_in[2];
    const float* att_src = (const float*)d_in[3];
    const float* att_dst = (const float*)d_in[4];
    const float* bias    = (const float*)d_in[5];
    const float* gamma   = (const float*)d_in[6];
    const float* beta    = (const float*)d_in[7];
    float* out = (float*)d_out;

    char* w = (char*)d_ws;
    float* sq   = (float*)w; w += (size_t)GN * 4;
    float* a_s  = (float*)w; w += (size_t)GN * GH * 4;
    float* a_d  = (float*)w; w += (size_t)GN * GH * 4;
    float* pv   = (float*)w; w += (size_t)GN * 6 * 4;
    int*   pi   = (int*)w;   w += (size_t)GN * 6 * 4;
    int*   fidx = (int*)w;   w += (size_t)GN * GK * 4;
    int*   cnt  = (int*)w;   w += (size_t)GN * 4;      // cnt|curs contiguous (one k_zero)
    int*   curs = (int*)w;   w += (size_t)GN * 4;
    int*   offs = (int*)w;   w += (size_t)(GN + 1) * 4;
    int*   elst = (int*)w;   w += (size_t)GN * GK * 4;
    size_t need = (size_t)((char*)w - (char*)d_ws);
    if (ws_size < need) return;   // diagnostic guard

    k_zero<<<(2 * GN + 255) / 256, 256, 0, stream>>>(cnt, 2 * GN);
    k_prep<<<GN / 4, 256, 0, stream>>>(x, sq);
    k_attn<<<GN / 16, 256, 0, stream>>>(x, W, att_src, att_dst, a_s, a_d);
    k_knn<<<(GN / 32) * 2, 256, 0, stream>>>(x, sq, pv, pi);
    k_knn_merge<<<GN / 256, 256, 0, stream>>>(pv, pi, fidx);
    k_count<<<GN * GK / 256, 256, 0, stream>>>(fidx, cnt);
    k_scan<<<1, 256, 0, stream>>>(cnt, offs);
    k_fill<<<GN * GK / 256, 256, 0, stream>>>(fidx, offs, curs, elst);
    k_gather<<<GN, 256, 0, stream>>>(offs, elst, a_s, a_d, x, W, bias, gamma, beta, out);
}

// Round 4
// 351.917 us; speedup vs baseline: 1.6400x; 1.6400x over previous
//
#include <hip/hip_runtime.h>
#include <hip/hip_bf16.h>
#include <math.h>

#define GN 8192
#define GD 128
#define GH 2
#define GK 3
#define NEG_SLOPE 0.2f
#define LN_EPS 1e-5f

using short8  = __attribute__((ext_vector_type(8)))  short;
using float16 = __attribute__((ext_vector_type(16))) float;

__device__ __forceinline__ float wred(float v) {
    #pragma unroll
    for (int o = 32; o > 0; o >>= 1) v += __shfl_xor(v, o, 64);
    return v;
}

// monotone float->uint encoding (ascending float -> ascending uint)
__device__ __forceinline__ unsigned fenc(float f) {
    unsigned b = __float_as_uint(f);
    return (b & 0x80000000u) ? ~b : (b | 0x80000000u);
}

__device__ __forceinline__ float rawbf2f(short s) {
    return __uint_as_float(((unsigned)(unsigned short)s) << 16);
}
__device__ __forceinline__ unsigned short f2rawbf(float f) {
    __hip_bfloat16 b = __float2bfloat16(f);
    unsigned short r; __builtin_memcpy(&r, &b, 2);
    return r;
}

__global__ void k_zero(int* p, int n) {
    int t = blockIdx.x * 256 + threadIdx.x;
    if (t < n) p[t] = 0;
}

// per-row squared norm. One wave per row.
__global__ void k_prep(const float* __restrict__ x, float* __restrict__ sq) {
    int row = blockIdx.x * 4 + (threadIdx.x >> 6);
    int lane = threadIdx.x & 63;
    const float* xr = x + (size_t)row * GD;
    float a = xr[lane], b = xr[lane + 64];
    float s = wred(a * a + b * b);
    if (lane == 0) sq[row] = s;
}

// xu[row][0..143] = [-2x (bf16, 128), sq_hi, sq_lo, zeros(14)]
__global__ void k_conv(const float* __restrict__ x, const float* __restrict__ sq,
                       unsigned short* __restrict__ xu) {
    int row = blockIdx.x, t = threadIdx.x;
    if (t < 128) {
        xu[(size_t)row * 144 + t] = f2rawbf(-2.f * x[(size_t)row * GD + t]);
    } else if (t < 144) {
        unsigned short o = 0;
        if (t == 128) o = f2rawbf(sq[row]);
        else if (t == 129) {
            float hi = rawbf2f((short)f2rawbf(sq[row]));
            o = f2rawbf(sq[row] - hi);
        }
        xu[(size_t)row * 144 + t] = o;
    }
}

// fused xp = x@W and attention dots a_s,a_d; 16 nodes per block, col t per thread.
__global__ void k_attn(const float* __restrict__ x,
                       const float* __restrict__ W,
                       const float* __restrict__ att_src,
                       const float* __restrict__ att_dst,
                       float* __restrict__ a_s, float* __restrict__ a_d) {
    __shared__ float xs[16][GD];
    __shared__ float xpls[16][256];
    int t = threadIdx.x;
    int i0 = blockIdx.x * 16;
    #pragma unroll
    for (int s = 0; s < 2; s++) {
        int f = t + 256 * s;
        int r = f >> 5, c4 = (f & 31) << 2;
        *(float4*)&xs[r][c4] = *(const float4*)(x + (size_t)(i0 + r) * GD + c4);
    }
    __syncthreads();
    float acc[16];
    #pragma unroll
    for (int r = 0; r < 16; r++) acc[r] = 0.f;
    for (int d = 0; d < GD; d++) {
        float wv = W[d * 256 + t];
        #pragma unroll
        for (int r = 0; r < 16; r++) acc[r] += xs[r][d] * wv;
    }
    #pragma unroll
    for (int r = 0; r < 16; r++) xpls[r][t] = acc[r];
    __syncthreads();
    int wid = t >> 6, lane = t & 63;
    for (int jj = 0; jj < 8; jj++) {
        int job = wid * 8 + jj;
        int r = job >> 1, h = job & 1;
        float v0 = xpls[r][h * 128 + lane];
        float v1 = xpls[r][h * 128 + 64 + lane];
        float s = v0 * att_src[h * GD + lane] + v1 * att_src[h * GD + lane + 64];
        float d = v0 * att_dst[h * GD + lane] + v1 * att_dst[h * GD + lane + 64];
        s = wred(s); d = wred(d);
        if (lane == 0) { a_s[(i0 + r) * 2 + h] = s; a_d[(i0 + r) * 2 + h] = d; }
    }
}

// register-resident sorted top-6 (ascending uint keys)
struct Top6 {
    unsigned a0, a1, a2, a3, a4, a5;
    __device__ __forceinline__ void init() { a0=a1=a2=a3=a4=a5=0xFFFFFFFFu; }
    __device__ __forceinline__ void insert(unsigned k) {
        if (k < a5) {
            if (k < a2) {
                if (k < a1) {
                    if (k < a0) { a5=a4;a4=a3;a3=a2;a2=a1;a1=a0;a0=k; }
                    else        { a5=a4;a4=a3;a3=a2;a2=a1;a1=k; }
                } else { a5=a4;a4=a3;a3=a2;a2=k; }
            } else {
                if (k < a4) {
                    if (k < a3) { a5=a4;a4=a3;a3=k; }
                    else        { a5=a4;a4=k; }
                } else { a5=k; }
            }
        }
    }
};

// MFMA candidate kNN: score_ij = sq_i - 2*x_i.x_j via augmented-K bf16 GEMM.
// grid (32 colblocks x 8 row-superblocks), 256 thr. Per column: running top-6
// over its superblock's 1024 rows, kept in the 2 lanes that own that column
// in the 32x32 C-layout. Key = (fenc(score) & ~0x1FFF) | row (13 bits).
__launch_bounds__(256, 1)
__global__ void k_gemm_topk(const unsigned short* __restrict__ xu,
                            unsigned* __restrict__ cand) {
    __shared__ unsigned short At[18 * 128 * 8];   // k-major: [kblk][row] 16B chunks
    int t = threadIdx.x;
    int bj = blockIdx.x, sb = blockIdx.y;
    int w = t >> 6, lane = t & 63, h = lane >> 5, n = lane & 31;
    int colbase = bj * 256 + 64 * w;

    // stationary B-frags: v_j = [x_j, 1, 1, 0...] derived from xu by * -0.5 + patch
    short8 bfrag[2][9];
    #pragma unroll
    for (int c = 0; c < 2; c++) {
        int col = colbase + 32 * c + n;
        #pragma unroll
        for (int kc = 0; kc < 9; kc++) {
            const unsigned short* p = xu + (size_t)col * 144 + (2 * kc + h) * 8;
            short8 raw = *(const short8*)p;
            short8 f;
            #pragma unroll
            for (int e = 0; e < 8; e++) f[e] = (short)f2rawbf(rawbf2f(raw[e]) * -0.5f);
            if (kc == 8 && h == 0) { f[0] = (short)0x3F80; f[1] = (short)0x3F80; }
            bfrag[c][kc] = f;
        }
    }

    Top6 T0, T1; T0.init(); T1.init();

    for (int it = 0; it < 8; it++) {
        int rowbase = sb * 1024 + it * 128;
        __syncthreads();
        for (int q = t; q < 18 * 128; q += 256) {
            int kb = q >> 7, r = q & 127;
            *(uint4*)&At[(kb * 128 + r) * 8] =
                *(const uint4*)(xu + (size_t)(rowbase + r) * 144 + kb * 8);
        }
        __syncthreads();

        float16 acc[4][2];
        #pragma unroll
        for (int rs = 0; rs < 4; rs++)
            #pragma unroll
            for (int c = 0; c < 2; c++)
                acc[rs][c] = (float16)(0.f);

        #pragma unroll
        for (int kc = 0; kc < 9; kc++) {
            short8 a[4];
            #pragma unroll
            for (int rs = 0; rs < 4; rs++)
                a[rs] = *(const short8*)&At[((2 * kc + h) * 128 + rs * 32 + n) * 8];
            #pragma unroll
            for (int rs = 0; rs < 4; rs++) {
                acc[rs][0] = __builtin_amdgcn_mfma_f32_32x32x16_bf16(a[rs], bfrag[0][kc], acc[rs][0], 0, 0, 0);
                acc[rs][1] = __builtin_amdgcn_mfma_f32_32x32x16_bf16(a[rs], bfrag[1][kc], acc[rs][1], 0, 0, 0);
            }
        }

        // selection: per acc frag, min-filter then detailed insert
        #pragma unroll
        for (int rs = 0; rs < 4; rs++) {
            #pragma unroll
            for (int c = 0; c < 2; c++) {
                float16 A = acc[rs][c];
                float m0 = fminf(fminf(fminf(A[0],A[1]),fminf(A[2],A[3])),
                                 fminf(fminf(A[4],A[5]),fminf(A[6],A[7])));
                float m1 = fminf(fminf(fminf(A[8],A[9]),fminf(A[10],A[11])),
                                 fminf(fminf(A[12],A[13]),fminf(A[14],A[15])));
                float mn = fminf(m0, m1);
                Top6& T = c ? T1 : T0;
                unsigned km = fenc(mn) & 0xFFFFE000u;
                if (km <= T.a5) {
                    int base = rowbase + rs * 32 + 4 * h;
                    #pragma unroll
                    for (int r = 0; r < 16; r++) {
                        int row = base + (r & 3) + 8 * (r >> 2);
                        unsigned key = (fenc(A[r]) & 0xFFFFE000u) | (unsigned)row;
                        T.insert(key);
                    }
                }
            }
        }
    }

    // merge the two h-halves of each column (lane <-> lane^32)
    {
        unsigned p0 = __shfl_xor((int)T0.a0, 32), p1 = __shfl_xor((int)T0.a1, 32),
                 p2 = __shfl_xor((int)T0.a2, 32), p3 = __shfl_xor((int)T0.a3, 32),
                 p4 = __shfl_xor((int)T0.a4, 32), p5 = __shfl_xor((int)T0.a5, 32);
        T0.insert(p0); T0.insert(p1); T0.insert(p2);
        T0.insert(p3); T0.insert(p4); T0.insert(p5);
        unsigned q0 = __shfl_xor((int)T1.a0, 32), q1 = __shfl_xor((int)T1.a1, 32),
                 q2 = __shfl_xor((int)T1.a2, 32), q3 = __shfl_xor((int)T1.a3, 32),
                 q4 = __shfl_xor((int)T1.a4, 32), q5 = __shfl_xor((int)T1.a5, 32);
        T1.insert(q0); T1.insert(q1); T1.insert(q2);
        T1.insert(q3); T1.insert(q4); T1.insert(q5);
    }
    if (lane < 32) {
        unsigned* c0 = cand + (size_t)(colbase + n) * 48 + sb * 6;
        c0[0]=T0.a0; c0[1]=T0.a1; c0[2]=T0.a2; c0[3]=T0.a3; c0[4]=T0.a4; c0[5]=T0.a5;
        unsigned* c1 = cand + (size_t)(colbase + 32 + n) * 48 + sb * 6;
        c1[0]=T1.a0; c1[1]=T1.a1; c1[2]=T1.a2; c1[3]=T1.a3; c1[4]=T1.a4; c1[5]=T1.a5;
    }
}

// exact fp32 refine: per column j, recompute d2 for 48 candidates, pick top-3
// with (d2, idx) lexicographic order (matches lax.top_k tie-breaking).
__global__ void k_refine(const unsigned* __restrict__ cand,
                         const float* __restrict__ x, const float* __restrict__ sq,
                         int* __restrict__ fidx) {
    __shared__ float xjs[GD];
    __shared__ float dv[48];
    __shared__ int   di[48];
    int j = blockIdx.x, t = threadIdx.x;
    if (t < GD) xjs[t] = x[(size_t)j * GD + t];
    __syncthreads();
    int wv = t >> 6, lane = t & 63;
    for (int c = wv; c < 48; c += 4) {
        int idx = (int)(cand[(size_t)j * 48 + c] & 8191u);
        const float* xi = x + (size_t)idx * GD;
        float p = xjs[lane] * xi[lane] + xjs[lane + 64] * xi[lane + 64];
        p = wred(p);
        if (lane == 0) { dv[c] = sq[j] + sq[idx] - 2.f * p; di[c] = idx; }
    }
    __syncthreads();
    if (t == 0) {
        float v0 = 1e30f, v1 = 1e30f, v2 = 1e30f;
        int   i0 = 0x7fffffff, i1 = 0x7fffffff, i2 = 0x7fffffff;
        for (int c = 0; c < 48; c++) {
            float v = dv[c]; int id = di[c];
            if (v < v2 || (v == v2 && id < i2)) {
                if (v < v1 || (v == v1 && id < i1)) {
                    v2 = v1; i2 = i1;
                    if (v < v0 || (v == v0 && id < i0)) { v1 = v0; i1 = i0; v0 = v; i0 = id; }
                    else                                 { v1 = v; i1 = id; }
                } else { v2 = v; i2 = id; }
            }
        }
        fidx[j * 3 + 0] = i0; fidx[j * 3 + 1] = i1; fidx[j * 3 + 2] = i2;
    }
}

__device__ __forceinline__ int clampN(int v) {
    return v < 0 ? 0 : (v >= GN ? GN - 1 : v);
}

__global__ void k_count(const int* __restrict__ fidx, int* __restrict__ cnt) {
    int eid = blockIdx.x * 256 + threadIdx.x;
    atomicAdd(&cnt[clampN(fidx[eid])], 1);
}

__global__ void k_scan(const int* __restrict__ cnt, int* __restrict__ offs) {
    __shared__ int part[256];
    int t = threadIdx.x;
    int base = t * 32;
    int loc[32];
    int s = 0;
    #pragma unroll
    for (int k = 0; k < 32; k++) { loc[k] = s; s += cnt[base + k]; }
    part[t] = s;
    __syncthreads();
    if (t == 0) {
        int run = 0;
        for (int k = 0; k < 256; k++) { int v = part[k]; part[k] = run; run += v; }
        offs[GN] = run;
    }
    __syncthreads();
    int b = part[t];
    #pragma unroll
    for (int k = 0; k < 32; k++) offs[base + k] = b + loc[k];
}

__global__ void k_fill(const int* __restrict__ fidx, const int* __restrict__ offs,
                       int* __restrict__ cursor, int* __restrict__ elist) {
    int eid = blockIdx.x * 256 + threadIdx.x;
    int i = clampN(fidx[eid]);
    int pos = atomicAdd(&cursor[i], 1);
    int slot = offs[i] + pos;
    if (slot < GN * GK) elist[slot] = eid / 3;
}

__global__ void k_gather(const int* __restrict__ offs, const int* __restrict__ elist,
                         const float* __restrict__ a_s, const float* __restrict__ a_d,
                         const float* __restrict__ x,
                         const float* __restrict__ W,
                         const float* __restrict__ bias,
                         const float* __restrict__ gamma,
                         const float* __restrict__ beta,
                         float* __restrict__ out) {
    __shared__ float red[256];
    __shared__ float zs[2][GD];
    __shared__ float os[256];
    int i = blockIdx.x, t = threadIdx.x;
    int h = t >> 7, c = t & 127;
    int start = offs[i];
    int deg = offs[i + 1] - start;
    float adh = a_d[i * 2 + h];

    float mx = -1e30f;
    for (int k = c; k < deg; k += 128) {
        int j = elist[start + k];
        float e = a_s[j * 2 + h] + adh;
        e = e >= 0.f ? e : NEG_SLOPE * e;
        mx = fmaxf(mx, e);
    }
    red[t] = mx;
    __syncthreads();
    #pragma unroll
    for (int s2 = 64; s2 > 0; s2 >>= 1) {
        if (c < s2) red[t] = fmaxf(red[t], red[t + s2]);
        __syncthreads();
    }
    float mh = red[h * 128];
    __syncthreads();

    float sm = 0.f;
    for (int k = c; k < deg; k += 128) {
        int j = elist[start + k];
        float e = a_s[j * 2 + h] + adh;
        e = e >= 0.f ? e : NEG_SLOPE * e;
        sm += expf(e - mh);
    }
    red[t] = sm;
    __syncthreads();
    #pragma unroll
    for (int s2 = 64; s2 > 0; s2 >>= 1) {
        if (c < s2) red[t] += red[t + s2];
        __syncthreads();
    }
    float dh = red[h * 128];
    __syncthreads();

    float z = 0.f;
    for (int k = 0; k < deg; k++) {
        int j = elist[start + k];
        float e = a_s[j * 2 + h] + adh;
        e = e >= 0.f ? e : NEG_SLOPE * e;
        float w = expf(e - mh);
        z += w * x[(size_t)j * GD + c];
    }
    zs[h][c] = z;
    __syncthreads();

    float o = 0.f;
    for (int d = 0; d < GD; d++) o += zs[h][d] * W[d * 256 + t];
    o /= dh;
    os[t] = o;
    __syncthreads();

    float y = 0.f;
    if (t < 128) y = 0.5f * (os[c] + os[c + 128]) + bias[c];
    float ps = (t < 128) ? y : 0.f;
    ps = wred(ps);
    if ((t & 63) == 0) red[t >> 6] = ps;
    __syncthreads();
    float mu = (red[0] + red[1] + red[2] + red[3]) * (1.f / 128.f);
    float cg = (t < 128) ? (y - mu) : 0.f;
    float pv2 = wred(cg * cg);
    if ((t & 63) == 0) red[8 + (t >> 6)] = pv2;
    __syncthreads();
    float var = (red[8] + red[9] + red[10] + red[11]) * (1.f / 128.f);
    if (t < 128) {
        float rs = 1.f / sqrtf(var + LN_EPS);
        float nv = cg * rs * gamma[c] + beta[c];
        nv = nv > 0.f ? nv : 0.f;
        out[(size_t)i * GD + c] = x[(size_t)i * GD + c] + nv;
    }
}

extern "C" void kernel_launch(void* const* d_in, const int* in_sizes, int n_in,
                              void* d_out, int out_size, void* d_ws, size_t ws_size,
                              hipStream_t stream) {
    const float* x       = (const float*)d_in[0];
    const float* W       = (const float*)d_in[2];
    const float* att_src = (const float*)d_in[3];
    const float* att_dst = (const float*)d_in[4];
    const float* bias    = (const float*)d_in[5];
    const float* gamma   = (const float*)d_in[6];
    const float* beta    = (const float*)d_in[7];
    float* out = (float*)d_out;

    char* w = (char*)d_ws;
    unsigned short* xu = (unsigned short*)w; w += (size_t)GN * 144 * 2;   // 2.25 MB (16B-aligned)
    unsigned* cand = (unsigned*)w;           w += (size_t)GN * 48 * 4;    // 1.5 MB
    float* sq   = (float*)w; w += (size_t)GN * 4;
    float* a_s  = (float*)w; w += (size_t)GN * GH * 4;
    float* a_d  = (float*)w; w += (size_t)GN * GH * 4;
    int*   fidx = (int*)w;   w += (size_t)GN * GK * 4;
    int*   cnt  = (int*)w;   w += (size_t)GN * 4;      // cnt|curs contiguous
    int*   curs = (int*)w;   w += (size_t)GN * 4;
    int*   offs = (int*)w;   w += (size_t)(GN + 1) * 4;
    int*   elst = (int*)w;   w += (size_t)GN * GK * 4;
    size_t need = (size_t)((char*)w - (char*)d_ws);
    if (ws_size < need) return;   // diagnostic guard

    k_zero<<<(2 * GN + 255) / 256, 256, 0, stream>>>(cnt, 2 * GN);
    k_prep<<<GN / 4, 256, 0, stream>>>(x, sq);
    k_conv<<<GN, 256, 0, stream>>>(x, sq, xu);
    k_attn<<<GN / 16, 256, 0, stream>>>(x, W, att_src, att_dst, a_s, a_d);
    k_gemm_topk<<<dim3(32, 8), 256, 0, stream>>>(xu, cand);
    k_refine<<<GN, 256, 0, stream>>>(cand, x, sq, fidx);
    k_count<<<GN * GK / 256, 256, 0, stream>>>(fidx, cnt);
    k_scan<<<1, 256, 0, stream>>>(cnt, offs);
    k_fill<<<GN * GK / 256, 256, 0, stream>>>(fidx, offs, curs, elst);
    k_gather<<<GN, 256, 0, stream>>>(offs, elst, a_s, a_d, x, W, bias, gamma, beta, out);
}

// Round 5
// 311.948 us; speedup vs baseline: 1.8502x; 1.1281x over previous
//
#include <hip/hip_runtime.h>
#include <hip/hip_bf16.h>
#include <math.h>

#define GN 8192
#define GD 128
#define GH 2
#define GK 3
#define NEG_SLOPE 0.2f
#define LN_EPS 1e-5f

using short8  = __attribute__((ext_vector_type(8)))  short;
using float16 = __attribute__((ext_vector_type(16))) float;

__device__ __forceinline__ float wred(float v) {
    #pragma unroll
    for (int o = 32; o > 0; o >>= 1) v += __shfl_xor(v, o, 64);
    return v;
}

__device__ __forceinline__ float rawbf2f(unsigned short s) {
    return __uint_as_float(((unsigned)s) << 16);
}
__device__ __forceinline__ unsigned short f2rawbf(float f) {
    __hip_bfloat16 b = __float2bfloat16(f);
    unsigned short r; __builtin_memcpy(&r, &b, 2);
    return r;
}
__device__ __forceinline__ unsigned umin2(unsigned a, unsigned b) { return a < b ? a : b; }
__device__ __forceinline__ unsigned umax2(unsigned a, unsigned b) { return a > b ? a : b; }

__global__ void k_zero(int* p, int n) {
    int t = blockIdx.x * 256 + threadIdx.x;
    if (t < n) p[t] = 0;
}

// one wave per row: sq[row], xa=[-2x bf16 | hi(sq+512) lo | 0..], xb=[x bf16 | 1 1 | 0..]
__global__ void k_conv(const float* __restrict__ x, float* __restrict__ sq,
                       unsigned short* __restrict__ xa, unsigned short* __restrict__ xb) {
    int row = blockIdx.x * 4 + (threadIdx.x >> 6);
    int lane = threadIdx.x & 63;
    const float* xr = x + (size_t)row * GD;
    float a0 = xr[lane], a1 = xr[lane + 64];
    float s = wred(a0 * a0 + a1 * a1);      // xor-butterfly: all lanes hold s
    unsigned short* ar = xa + (size_t)row * 144;
    unsigned short* br = xb + (size_t)row * 144;
    ar[lane] = f2rawbf(-2.f * a0); ar[lane + 64] = f2rawbf(-2.f * a1);
    br[lane] = f2rawbf(a0);        br[lane + 64] = f2rawbf(a1);
    if (lane < 16) {
        unsigned short av = 0, bv = 0;
        if (lane == 0)      { av = f2rawbf(s + 512.f); bv = 0x3F80; }
        else if (lane == 1) { float hi = rawbf2f(f2rawbf(s + 512.f));
                              av = f2rawbf(s + 512.f - hi); bv = 0x3F80; }
        ar[128 + lane] = av; br[128 + lane] = bv;
        if (lane == 0) sq[row] = s;
    }
}

// fused xp = x@W and attention dots a_s,a_d; 16 nodes per block, col t per thread.
__global__ void k_attn(const float* __restrict__ x,
                       const float* __restrict__ W,
                       const float* __restrict__ att_src,
                       const float* __restrict__ att_dst,
                       float* __restrict__ a_s, float* __restrict__ a_d) {
    __shared__ float xs[16][GD];
    __shared__ float xpls[16][256];
    int t = threadIdx.x;
    int i0 = blockIdx.x * 16;
    #pragma unroll
    for (int s = 0; s < 2; s++) {
        int f = t + 256 * s;
        int r = f >> 5, c4 = (f & 31) << 2;
        *(float4*)&xs[r][c4] = *(const float4*)(x + (size_t)(i0 + r) * GD + c4);
    }
    __syncthreads();
    float acc[16];
    #pragma unroll
    for (int r = 0; r < 16; r++) acc[r] = 0.f;
    for (int d = 0; d < GD; d++) {
        float wv = W[d * 256 + t];
        #pragma unroll
        for (int r = 0; r < 16; r++) acc[r] += xs[r][d] * wv;
    }
    #pragma unroll
    for (int r = 0; r < 16; r++) xpls[r][t] = acc[r];
    __syncthreads();
    int wid = t >> 6, lane = t & 63;
    for (int jj = 0; jj < 8; jj++) {
        int job = wid * 8 + jj;
        int r = job >> 1, h = job & 1;
        float v0 = xpls[r][h * 128 + lane];
        float v1 = xpls[r][h * 128 + 64 + lane];
        float s = v0 * att_src[h * GD + lane] + v1 * att_src[h * GD + lane + 64];
        float d = v0 * att_dst[h * GD + lane] + v1 * att_dst[h * GD + lane + 64];
        s = wred(s); d = wred(d);
        if (lane == 0) { a_s[(i0 + r) * 2 + h] = s; a_d[(i0 + r) * 2 + h] = d; }
    }
}

// sorted top-6 of unsigned keys, branchless bubble insert (11 min/max)
struct Top6 {
    unsigned a0, a1, a2, a3, a4, a5;
    __device__ __forceinline__ void init() { a0=a1=a2=a3=a4=a5=0xFFFFFFFFu; }
    __device__ __forceinline__ void insert(unsigned k) {
        unsigned m0 = umax2(a0, k);  a0 = umin2(a0, k);
        unsigned m1 = umax2(a1, m0); a1 = umin2(a1, m0);
        unsigned m2 = umax2(a2, m1); a2 = umin2(a2, m1);
        unsigned m3 = umax2(a3, m2); a3 = umin2(a3, m2);
        unsigned m4 = umax2(a4, m3); a4 = umin2(a4, m3);
        a5 = umin2(a5, m4);
    }
};

// MFMA candidate kNN. score'_ij = 512 + sq_i - 2 x_i.x_j (always > 0 -> raw float
// bits are order-monotone). Per column j: top-6 keys per 1024-row superblock.
// key = (bits & 0xFFFFE000) | row. 1 column-group of 32 per wave.
__launch_bounds__(256, 2)
__global__ void k_gemm_topk(const unsigned short* __restrict__ xa,
                            const unsigned short* __restrict__ xb,
                            unsigned* __restrict__ cand) {
    __shared__ unsigned short At[18 * 128 * 8];   // 36 KB, k-major chunks
    int t = threadIdx.x;
    int w = t >> 6, lane = t & 63, h = lane >> 5, n = lane & 31;
    int col = blockIdx.x * 128 + w * 32 + n;
    int sb = blockIdx.y;

    short8 bfrag[9];
    #pragma unroll
    for (int kc = 0; kc < 9; kc++)
        bfrag[kc] = *(const short8*)(xb + (size_t)col * 144 + (2 * kc + h) * 8);

    Top6 T; T.init();

    for (int it = 0; it < 8; it++) {
        int rowbase = sb * 1024 + it * 128;
        __syncthreads();
        #pragma unroll
        for (int q = t; q < 18 * 128; q += 256) {
            int kb = q >> 7, r = q & 127;
            *(uint4*)&At[(kb * 128 + r) * 8] =
                *(const uint4*)(xa + (size_t)(rowbase + r) * 144 + kb * 8);
        }
        __syncthreads();

        float16 acc[4];
        #pragma unroll
        for (int rs = 0; rs < 4; rs++) acc[rs] = (float16)(0.f);

        #pragma unroll
        for (int kc = 0; kc < 9; kc++) {
            short8 a[4];
            #pragma unroll
            for (int rs = 0; rs < 4; rs++)
                a[rs] = *(const short8*)&At[((2 * kc + h) * 128 + rs * 32 + n) * 8];
            #pragma unroll
            for (int rs = 0; rs < 4; rs++)
                acc[rs] = __builtin_amdgcn_mfma_f32_32x32x16_bf16(a[rs], bfrag[kc], acc[rs], 0, 0, 0);
        }

        #pragma unroll
        for (int rs = 0; rs < 4; rs++) {
            float16 A = acc[rs];
            int rb = rowbase + 4 * h + rs * 32;
            unsigned kk[16];
            #pragma unroll
            for (int r = 0; r < 16; r++)
                kk[r] = (__float_as_uint(A[r]) & 0xFFFFE000u) |
                        (unsigned)(rb + (r & 3) + 8 * (r >> 2));
            unsigned ma = umin2(umin2(umin2(kk[0],kk[1]),umin2(kk[2],kk[3])),
                                umin2(umin2(kk[4],kk[5]),umin2(kk[6],kk[7])));
            unsigned mb = umin2(umin2(umin2(kk[8],kk[9]),umin2(kk[10],kk[11])),
                                umin2(umin2(kk[12],kk[13]),umin2(kk[14],kk[15])));
            if (umin2(ma, mb) <= T.a5) {
                #pragma unroll
                for (int r = 0; r < 16; r++) T.insert(kk[r]);
            }
        }
    }

    // merge h-halves of each column (snapshot partner's 6, then insert)
    unsigned p0 = (unsigned)__shfl_xor((int)T.a0, 32), p1 = (unsigned)__shfl_xor((int)T.a1, 32),
             p2 = (unsigned)__shfl_xor((int)T.a2, 32), p3 = (unsigned)__shfl_xor((int)T.a3, 32),
             p4 = (unsigned)__shfl_xor((int)T.a4, 32), p5 = (unsigned)__shfl_xor((int)T.a5, 32);
    T.insert(p0); T.insert(p1); T.insert(p2); T.insert(p3); T.insert(p4); T.insert(p5);

    if (h == 0) {
        unsigned* c0 = cand + (size_t)col * 48 + sb * 6;
        c0[0]=T.a0; c0[1]=T.a1; c0[2]=T.a2; c0[3]=T.a3; c0[4]=T.a4; c0[5]=T.a5;
    }
}

__device__ __forceinline__ int clampN(int v) {
    return v < 0 ? 0 : (v >= GN ? GN - 1 : v);
}

// exact fp32 refine + degree count. Per column j: exact d2 for 48 candidates,
// top-3 with (d2, idx) lexicographic order (matches lax.top_k tie-break).
__global__ void k_refine(const unsigned* __restrict__ cand,
                         const float* __restrict__ x, const float* __restrict__ sq,
                         int* __restrict__ fidx, int* __restrict__ cnt) {
    __shared__ float xjs[GD];
    __shared__ float dv[48];
    __shared__ int   di[48];
    int j = blockIdx.x, t = threadIdx.x;
    if (t < GD) xjs[t] = x[(size_t)j * GD + t];
    __syncthreads();
    int wv = t >> 6, lane = t & 63;
    for (int c = wv; c < 48; c += 4) {
        int idx = (int)(cand[(size_t)j * 48 + c] & 8191u);
        const float* xi = x + (size_t)idx * GD;
        float p = xjs[lane] * xi[lane] + xjs[lane + 64] * xi[lane + 64];
        p = wred(p);
        if (lane == 0) { dv[c] = sq[j] + sq[idx] - 2.f * p; di[c] = idx; }
    }
    __syncthreads();
    if (t == 0) {
        float v0 = 1e30f, v1 = 1e30f, v2 = 1e30f;
        int   i0 = 0x7fffffff, i1 = 0x7fffffff, i2 = 0x7fffffff;
        for (int c = 0; c < 48; c++) {
            float v = dv[c]; int id = di[c];
            if (v < v2 || (v == v2 && id < i2)) {
                if (v < v1 || (v == v1 && id < i1)) {
                    v2 = v1; i2 = i1;
                    if (v < v0 || (v == v0 && id < i0)) { v1 = v0; i1 = i0; v0 = v; i0 = id; }
                    else                                 { v1 = v; i1 = id; }
                } else { v2 = v; i2 = id; }
            }
        }
        i0 = clampN(i0); i1 = clampN(i1); i2 = clampN(i2);
        fidx[j * 3 + 0] = i0; fidx[j * 3 + 1] = i1; fidx[j * 3 + 2] = i2;
        atomicAdd(&cnt[i0], 1); atomicAdd(&cnt[i1], 1); atomicAdd(&cnt[i2], 1);
    }
}

// single-block exclusive scan of cnt[8192] -> offs[0..8192]
__global__ void k_scan(const int* __restrict__ cnt, int* __restrict__ offs) {
    __shared__ int part[256];
    int t = threadIdx.x;
    int base = t * 32;
    int loc[32];
    int s = 0;
    #pragma unroll
    for (int k = 0; k < 32; k++) { loc[k] = s; s += cnt[base + k]; }
    part[t] = s;
    __syncthreads();
    if (t == 0) {
        int run = 0;
        for (int k = 0; k < 256; k++) { int v = part[k]; part[k] = run; run += v; }
        offs[GN] = run;
    }
    __syncthreads();
    int b = part[t];
    #pragma unroll
    for (int k = 0; k < 32; k++) offs[base + k] = b + loc[k];
}

__global__ void k_fill(const int* __restrict__ fidx, const int* __restrict__ offs,
                       int* __restrict__ cursor, int* __restrict__ elist) {
    int eid = blockIdx.x * 256 + threadIdx.x;
    int i = clampN(fidx[eid]);
    int pos = atomicAdd(&cursor[i], 1);
    int slot = offs[i] + pos;
    if (slot < GN * GK) elist[slot] = eid / 3;
}

// fused: per-dst softmax -> z (LDS) -> z@W -> head-mean+bias -> LN -> ReLU -> residual.
// 16 nodes per block; W read once per block (512 blocks).
__global__ void k_gatherout(const int* __restrict__ offs, const int* __restrict__ elst,
                            const float* __restrict__ a_s, const float* __restrict__ a_d,
                            const float* __restrict__ x, const float* __restrict__ W,
                            const float* __restrict__ bias, const float* __restrict__ gamma,
                            const float* __restrict__ beta, float* __restrict__ out) {
    __shared__ float zs[16][256];
    __shared__ float os[16][256];
    __shared__ float smM[16][2];
    __shared__ float smD[16][2];
    int t = threadIdx.x;
    int i0 = blockIdx.x * 16;
    int h = t >> 7, c = t & 127;

    if (t < 32) {
        int r = t >> 1, hh = t & 1, node = i0 + r;
        int s = offs[node], e = offs[node + 1];
        float adh = a_d[node * 2 + hh];
        float mx = -1e30f;
        for (int k = s; k < e; k++) {
            float ee = a_s[elst[k] * 2 + hh] + adh;
            ee = ee >= 0.f ? ee : NEG_SLOPE * ee;
            mx = fmaxf(mx, ee);
        }
        float dd = 0.f;
        for (int k = s; k < e; k++) {
            float ee = a_s[elst[k] * 2 + hh] + adh;
            ee = ee >= 0.f ? ee : NEG_SLOPE * ee;
            dd += expf(ee - mx);
        }
        smM[r][hh] = mx; smD[r][hh] = dd;
    }
    __syncthreads();

    for (int r = 0; r < 16; r++) {
        int node = i0 + r;
        int s = offs[node], e = offs[node + 1];
        float adh = a_d[node * 2 + h];
        float mh = smM[r][h], dh = smD[r][h];
        float z = 0.f;
        for (int k = s; k < e; k++) {
            int j = elst[k];
            float ee = a_s[j * 2 + h] + adh;
            ee = ee >= 0.f ? ee : NEG_SLOPE * ee;
            z += expf(ee - mh) * x[(size_t)j * GD + c];
        }
        zs[r][h * 128 + c] = z / dh;
    }
    __syncthreads();

    float acc[16];
    #pragma unroll
    for (int r = 0; r < 16; r++) acc[r] = 0.f;
    for (int d = 0; d < GD; d++) {
        float wv = W[d * 256 + t];
        #pragma unroll
        for (int r = 0; r < 16; r++) acc[r] += zs[r][h * 128 + d] * wv;
    }
    #pragma unroll
    for (int r = 0; r < 16; r++) os[r][t] = acc[r];
    __syncthreads();

    int wv = t >> 6, lane = t & 63;
    #pragma unroll
    for (int rr = 0; rr < 4; rr++) {
        int r = wv * 4 + rr;
        int node = i0 + r;
        float y0 = 0.5f * (os[r][lane] + os[r][128 + lane]) + bias[lane];
        float y1 = 0.5f * (os[r][lane + 64] + os[r][192 + lane]) + bias[lane + 64];
        float mu = wred(y0 + y1) * (1.f / 128.f);
        float c0 = y0 - mu, c1 = y1 - mu;
        float var = wred(c0 * c0 + c1 * c1) * (1.f / 128.f);
        float rs2 = 1.f / sqrtf(var + LN_EPS);
        float n0 = c0 * rs2 * gamma[lane] + beta[lane];
        float n1 = c1 * rs2 * gamma[lane + 64] + beta[lane + 64];
        n0 = n0 > 0.f ? n0 : 0.f;
        n1 = n1 > 0.f ? n1 : 0.f;
        out[(size_t)node * GD + lane]      = x[(size_t)node * GD + lane] + n0;
        out[(size_t)node * GD + lane + 64] = x[(size_t)node * GD + lane + 64] + n1;
    }
}

extern "C" void kernel_launch(void* const* d_in, const int* in_sizes, int n_in,
                              void* d_out, int out_size, void* d_ws, size_t ws_size,
                              hipStream_t stream) {
    const float* x       = (const float*)d_in[0];
    const float* W       = (const float*)d_in[2];
    const float* att_src = (const float*)d_in[3];
    const float* att_dst = (const float*)d_in[4];
    const float* bias    = (const float*)d_in[5];
    const float* gamma   = (const float*)d_in[6];
    const float* beta    = (const float*)d_in[7];
    float* out = (float*)d_out;

    char* w = (char*)d_ws;
    unsigned short* xa = (unsigned short*)w; w += (size_t)GN * 144 * 2;   // 2.25 MB
    unsigned short* xb = (unsigned short*)w; w += (size_t)GN * 144 * 2;   // 2.25 MB
    unsigned* cand = (unsigned*)w;           w += (size_t)GN * 48 * 4;    // 1.5 MB
    float* sq   = (float*)w; w += (size_t)GN * 4;
    float* a_s  = (float*)w; w += (size_t)GN * GH * 4;
    float* a_d  = (float*)w; w += (size_t)GN * GH * 4;
    int*   fidx = (int*)w;   w += (size_t)GN * GK * 4;
    int*   cnt  = (int*)w;   w += (size_t)GN * 4;      // cnt|curs contiguous
    int*   curs = (int*)w;   w += (size_t)GN * 4;
    int*   offs = (int*)w;   w += (size_t)(GN + 1) * 4;
    int*   elst = (int*)w;   w += (size_t)GN * GK * 4;
    size_t need = (size_t)((char*)w - (char*)d_ws);
    if (ws_size < need) return;   // diagnostic guard

    k_zero<<<(2 * GN + 255) / 256, 256, 0, stream>>>(cnt, 2 * GN);
    k_conv<<<GN / 4, 256, 0, stream>>>(x, sq, xa, xb);
    k_attn<<<GN / 16, 256, 0, stream>>>(x, W, att_src, att_dst, a_s, a_d);
    k_gemm_topk<<<dim3(64, 8), 256, 0, stream>>>(xa, xb, cand);
    k_refine<<<GN, 256, 0, stream>>>(cand, x, sq, fidx, cnt);
    k_scan<<<1, 256, 0, stream>>>(cnt, offs);
    k_fill<<<GN * GK / 256, 256, 0, stream>>>(fidx, offs, curs, elst);
    k_gatherout<<<GN / 16, 256, 0, stream>>>(offs, elst, a_s, a_d, x, W, bias, gamma, beta, out);
}